// Round 4
// baseline (327.216 us; speedup 1.0000x reference)
//
#include <hip/hip_runtime.h>
#include <math.h>

#define NODES 6272
#define BATCH 64
#define NCAPS 10
#define CIN   8
#define COUT  16
#define NWB   16                 // nodes per block
#define CHUNKS (NODES / NWB)     // 392
#define PART_STRIDE 20           // 16 acc + 1 z + pad

// ---------------- x transpose: x[b][n][i] -> xT[n][b][i] ----------------
__global__ __launch_bounds__(256) void k_xpose(const float* __restrict__ x,
                                               float* __restrict__ xT) {
    int g = blockIdx.x * 256 + threadIdx.x;      // g in [0, NODES*BATCH)
    int b = g & 63;
    int n = g >> 6;
    const float* xp = x + (size_t)b * (NODES * CIN) + (size_t)n * CIN;
    float4 a0 = *reinterpret_cast<const float4*>(xp);
    float4 a1 = *reinterpret_cast<const float4*>(xp + 4);
    float4* op = reinterpret_cast<float4*>(xT + (size_t)g * 8);
    op[0] = a0;
    op[1] = a1;
}

// ---------------- fused routing pass (o-split lanes, no LDS in hot loop) ----
// Block = 4 waves, owns (c, 16-node chunk). Wave w: bh=w&1 (b-half), ws=w>>1
// (node parity). Lane = (bl = lane&31 -> b = bh*32+bl, oh = lane>>5 -> o-half).
// Each lane computes u[o] for its 8 o's; logit joined across o-halves via
// shfl_xor(32). W loads: 2 distinct addrs/wave -> 64B coalesced L2 hits.
template<int PASS>
__global__ __launch_bounds__(256) void k_pass(const float* __restrict__ xT,
                                              const float* __restrict__ W,
                                              const float* __restrict__ vsum,
                                              float* __restrict__ part) {
    __shared__ float Rbuf[2][32][PART_STRIDE];   // 5 KB cross-wave reduce

    int bid  = blockIdx.x;                 // 0 .. 3919
    int w    = threadIdx.x >> 6;           // 0..3
    int bh   = w & 1;
    int ws   = w >> 1;
    int lane = threadIdx.x & 63;
    int bl   = lane & 31;
    int oh   = lane >> 5;                  // o-half: 0 -> o0..7, 1 -> o8..15
    int b    = bh * 32 + bl;
    int c    = bid % NCAPS;                // c fastest: x-chunk L2 reuse
    int ch   = bid / NCAPS;
    int n0   = ch * NWB;

    float vs[8];
    if (PASS > 0) {
        const float* vp = vsum + ((size_t)(c * BATCH) + b) * COUT + oh * 8;
        #pragma unroll
        for (int j = 0; j < 8; ++j) vs[j] = vp[j];
    }

    float acc[8];
    #pragma unroll
    for (int j = 0; j < 8; ++j) acc[j] = 0.f;
    float z = 0.f;

    #pragma unroll 2
    for (int nn = ws; nn < NWB; nn += 2) {
        int n = n0 + nn;

        // x row for this b (lanes bl and bl+32 share addr -> coalesced bcast)
        const float4* xp = reinterpret_cast<const float4*>(xT + ((size_t)n * 64 + b) * 8);
        float4 xa = xp[0], xb = xp[1];
        float xv[8] = {xa.x, xa.y, xa.z, xa.w, xb.x, xb.y, xb.z, xb.w};

        // W row slice for this o-half: 2 distinct addrs per wave
        const float* wp = W + ((size_t)c * NODES + n) * (CIN * COUT) + oh * 8;

        float u[8];
        #pragma unroll
        for (int j = 0; j < 8; ++j) u[j] = 0.f;
        #pragma unroll
        for (int i = 0; i < CIN; ++i) {
            float4 w0 = *reinterpret_cast<const float4*>(wp + i * COUT);
            float4 w1 = *reinterpret_cast<const float4*>(wp + i * COUT + 4);
            float xi = xv[i];
            u[0] = fmaf(xi, w0.x, u[0]);  u[1] = fmaf(xi, w0.y, u[1]);
            u[2] = fmaf(xi, w0.z, u[2]);  u[3] = fmaf(xi, w0.w, u[3]);
            u[4] = fmaf(xi, w1.x, u[4]);  u[5] = fmaf(xi, w1.y, u[5]);
            u[6] = fmaf(xi, w1.z, u[6]);  u[7] = fmaf(xi, w1.w, u[7]);
        }

        if (PASS == 0) {
            #pragma unroll
            for (int j = 0; j < 8; ++j) acc[j] += u[j];
            z += 1.f;
        } else {
            float lg = 0.f;
            #pragma unroll
            for (int j = 0; j < 8; ++j) lg = fmaf(u[j], vs[j], lg);
            lg += __shfl_xor(lg, 32);          // join o-halves: full dot over 16
            float wgt = __expf(lg);            // |lg| < ~22 worst case: safe
            z += wgt;
            #pragma unroll
            for (int j = 0; j < 8; ++j) acc[j] = fmaf(wgt, u[j], acc[j]);
        }
    }

    // cross-wave reduce over node-parity (ws): ws=1 writes, ws=0 adds + stores
    if (ws == 1) {
        float* rp = &Rbuf[bh][bl][oh * 8];
        reinterpret_cast<float4*>(rp)[0] = make_float4(acc[0], acc[1], acc[2], acc[3]);
        reinterpret_cast<float4*>(rp)[1] = make_float4(acc[4], acc[5], acc[6], acc[7]);
        if (oh == 0) Rbuf[bh][bl][16] = z;
    }
    __syncthreads();
    if (ws == 0) {
        const float* rp = &Rbuf[bh][bl][oh * 8];
        #pragma unroll
        for (int j = 0; j < 8; ++j) acc[j] += rp[j];
        z += Rbuf[bh][bl][16];

        float* pp = part + ((size_t)bid * BATCH + b) * PART_STRIDE + oh * 8;
        reinterpret_cast<float4*>(pp)[0] = make_float4(acc[0], acc[1], acc[2], acc[3]);
        reinterpret_cast<float4*>(pp)[1] = make_float4(acc[4], acc[5], acc[6], acc[7]);
        if (oh == 0) pp[16] = z;               // pp already +0 for oh==0
    }
}

// ---------------- merge partials, squash, update vsum / write out ----------------
template<int PASS>
__global__ __launch_bounds__(256) void k_merge(const float* __restrict__ part,
                                               float* __restrict__ vsum,
                                               float* __restrict__ out) {
    __shared__ float R[3][PART_STRIDE];
    int bid = blockIdx.x;                  // 0..639 = c*64 + b
    int c = bid >> 6;
    int b = bid & 63;
    int t = threadIdx.x;

    float a[COUT];
    #pragma unroll
    for (int o = 0; o < COUT; ++o) a[o] = 0.f;
    float z = 0.f;

    for (int ch = t; ch < CHUNKS; ch += 256) {
        const float* pp = part + ((size_t)(ch * NCAPS + c) * BATCH + b) * PART_STRIDE;
        float4 q0 = reinterpret_cast<const float4*>(pp)[0];
        float4 q1 = reinterpret_cast<const float4*>(pp)[1];
        float4 q2 = reinterpret_cast<const float4*>(pp)[2];
        float4 q3 = reinterpret_cast<const float4*>(pp)[3];
        a[0]+=q0.x; a[1]+=q0.y; a[2]+=q0.z; a[3]+=q0.w;
        a[4]+=q1.x; a[5]+=q1.y; a[6]+=q1.z; a[7]+=q1.w;
        a[8]+=q2.x; a[9]+=q2.y; a[10]+=q2.z; a[11]+=q2.w;
        a[12]+=q3.x; a[13]+=q3.y; a[14]+=q3.z; a[15]+=q3.w;
        z += pp[16];
    }

    #pragma unroll
    for (int off = 32; off >= 1; off >>= 1) {
        z += __shfl_xor(z, off);
        #pragma unroll
        for (int o = 0; o < COUT; ++o) a[o] += __shfl_xor(a[o], off);
    }

    int wid = t >> 6, lane = t & 63;
    if (lane == 0 && wid > 0) {
        #pragma unroll
        for (int o = 0; o < COUT; ++o) R[wid - 1][o] = a[o];
        R[wid - 1][16] = z;
    }
    __syncthreads();
    if (t == 0) {
        #pragma unroll
        for (int r = 0; r < 3; ++r) {
            #pragma unroll
            for (int o = 0; o < COUT; ++o) a[o] += R[r][o];
            z += R[r][16];
        }
        float s[COUT];
        float sn = 0.f;
        #pragma unroll
        for (int o = 0; o < COUT; ++o) { s[o] = a[o] / z; sn += s[o] * s[o]; }
        float scale = sn / ((1.f + sn) * sqrtf(sn));   // |s|^2/(1+|s|^2) * 1/|s|
        if (PASS == 0) {
            float* vp = vsum + ((size_t)(c * BATCH) + b) * COUT;
            #pragma unroll
            for (int o = 0; o < COUT; ++o) vp[o] = scale * s[o];
        } else if (PASS == 1) {
            float* vp = vsum + ((size_t)(c * BATCH) + b) * COUT;
            #pragma unroll
            for (int o = 0; o < COUT; ++o) vp[o] += scale * s[o];
        } else {
            float* op = out + ((size_t)(b * NCAPS + c)) * COUT;
            #pragma unroll
            for (int o = 0; o < COUT; ++o) op[o] = scale * s[o];
        }
    }
}

extern "C" void kernel_launch(void* const* d_in, const int* in_sizes, int n_in,
                              void* d_out, int out_size, void* d_ws, size_t ws_size,
                              hipStream_t stream) {
    const float* x = (const float*)d_in[0];   // [64, 6272, 8]
    const float* W = (const float*)d_in[1];   // [10, 6272, 8, 16]
    float* out = (float*)d_out;               // [64, 10, 1, 16]
    float* ws  = (float*)d_ws;

    // ws layout (floats): xT [6272*64*8] | part [3920*64*20] | vsum [10*64*16]
    float* xT   = ws;
    float* part = ws + (size_t)NODES * BATCH * CIN;
    float* vsum = part + (size_t)NCAPS * CHUNKS * BATCH * PART_STRIDE;

    k_xpose<<<(NODES * BATCH) / 256, 256, 0, stream>>>(x, xT);

    k_pass<0><<<NCAPS * CHUNKS, 256, 0, stream>>>(xT, W, vsum, part);
    k_merge<0><<<NCAPS * BATCH, 256, 0, stream>>>(part, vsum, out);

    k_pass<1><<<NCAPS * CHUNKS, 256, 0, stream>>>(xT, W, vsum, part);
    k_merge<1><<<NCAPS * BATCH, 256, 0, stream>>>(part, vsum, out);

    k_pass<2><<<NCAPS * CHUNKS, 256, 0, stream>>>(xT, W, vsum, part);
    k_merge<2><<<NCAPS * BATCH, 256, 0, stream>>>(part, vsum, out);
}

// Round 6
// 225.830 us; speedup vs baseline: 1.4490x; 1.4490x over previous
//
#include <hip/hip_runtime.h>
#include <math.h>

#define NODES 6272
#define BATCH 64
#define NCAPS 10
#define CIN   8
#define COUT  16
#define SLICE_N   8                       // nodes per wave in k_pass
#define NSLICES   (NODES / SLICE_N)       // 784
#define PART_STRIDE 20                    // 16 acc + 1 z + pad

// ws uint counts
#define WUINTS  (NCAPS * NODES * 64)      // Whp: [c][n][o][i2] packed f16 pairs = 4,014,080
#define XUINTS  (NODES * BATCH * 4)       // xTh: [n][b][i2]                    = 1,604,096
#define PREP_TOTAL (WUINTS + XUINTS)      // 5,618,176

// half2 type EXACTLY as the builtins declare it (V2h): derive via decltype.
typedef decltype(__builtin_amdgcn_cvt_pkrtz(0.f, 0.f)) h2t;

static __device__ inline unsigned packh2(float a, float b) {
    union { h2t h; unsigned u; } cv;
    cv.h = __builtin_amdgcn_cvt_pkrtz(a, b);
    return cv.u;
}
static __device__ inline float dot2(unsigned a, unsigned b, float c) {
    union { unsigned u; h2t h; } A, B;
    A.u = a; B.u = b;
    return __builtin_amdgcn_fdot2(A.h, B.h, c, false);
}

// ---------------- prep: W -> Whp (f16 pairs, [c][n][o][i2]), x -> xTh ([n][b][i2]) ----
__global__ __launch_bounds__(256) void k_prep(const float* __restrict__ x,
                                              const float* __restrict__ W,
                                              unsigned* __restrict__ Whp,
                                              unsigned* __restrict__ xTh) {
    for (long long g = blockIdx.x * 256 + threadIdx.x; g < PREP_TOTAL;
         g += (long long)gridDim.x * 256) {
        if (g < WUINTS) {
            int i2 = g & 3;
            int o  = (g >> 2) & 15;
            long long cn = g >> 6;                 // c*NODES + n
            const float* wp = W + cn * (CIN * COUT) + o;
            float a = wp[(2 * i2) * COUT];
            float b = wp[(2 * i2 + 1) * COUT];
            Whp[g] = packh2(a, b);
        } else {
            long long G = g - WUINTS;
            int i2 = G & 3;
            int b  = (G >> 2) & 63;
            int n  = (int)(G >> 8);
            const float* xp = x + ((size_t)b * NODES + n) * CIN + 2 * i2;
            xTh[G] = packh2(xp[0], xp[1]);
        }
    }
}

// ---------------- fused routing pass ----------------
// wave = (c, slice of 8 nodes); lane = b. Full 16 outputs per lane; acc over n
// in registers (no cross-lane reduce). W row wave-uniform (broadcast loads).
template<int PASS>
__global__ __launch_bounds__(256) void k_pass(const unsigned* __restrict__ Whp,
                                              const unsigned* __restrict__ xTh,
                                              const float* __restrict__ vsum,
                                              float* __restrict__ part) {
    int wid  = __builtin_amdgcn_readfirstlane(blockIdx.x * 4 + (threadIdx.x >> 6));
    int lane = threadIdx.x & 63;                 // = b
    int c     = wid % NCAPS;
    int slice = wid / NCAPS;
    int n0    = slice * SLICE_N;

    float vs[COUT];
    if (PASS > 0) {
        const float4* vp = reinterpret_cast<const float4*>(
            vsum + ((size_t)(c * BATCH) + lane) * COUT);
        float4 v0 = vp[0], v1 = vp[1], v2 = vp[2], v3 = vp[3];
        vs[0]=v0.x; vs[1]=v0.y; vs[2]=v0.z; vs[3]=v0.w;
        vs[4]=v1.x; vs[5]=v1.y; vs[6]=v1.z; vs[7]=v1.w;
        vs[8]=v2.x; vs[9]=v2.y; vs[10]=v2.z; vs[11]=v2.w;
        vs[12]=v3.x; vs[13]=v3.y; vs[14]=v3.z; vs[15]=v3.w;
    }

    float acc[COUT];
    #pragma unroll
    for (int o = 0; o < COUT; ++o) acc[o] = 0.f;
    float z = 0.f;

    for (int nn = 0; nn < SLICE_N; ++nn) {
        int n = n0 + nn;
        // wave-uniform W row: 16 x uint4 (o-major, 4 i-pairs each)
        const uint4* wp = reinterpret_cast<const uint4*>(
            Whp + ((size_t)(c * NODES + n)) * 64);
        uint4 wq[16];
        #pragma unroll
        for (int o = 0; o < COUT; ++o) wq[o] = wp[o];

        // lane-private x row: 16B/lane, fully coalesced (1 KB/wave/instr)
        uint4 xq = *reinterpret_cast<const uint4*>(
            xTh + ((size_t)n * BATCH + lane) * 4);

        float u[COUT];
        #pragma unroll
        for (int o = 0; o < COUT; ++o) {
            u[o] = dot2(xq.w, wq[o].w,
                   dot2(xq.z, wq[o].z,
                   dot2(xq.y, wq[o].y,
                   dot2(xq.x, wq[o].x, 0.f))));
        }

        if (PASS == 0) {
            #pragma unroll
            for (int o = 0; o < COUT; ++o) acc[o] += u[o];
            z += 1.f;
        } else {
            float lg = 0.f;
            #pragma unroll
            for (int o = 0; o < COUT; ++o) lg = fmaf(u[o], vs[o], lg);
            float w = __expf(lg);                // |lg| small; fp32-safe
            z += w;
            #pragma unroll
            for (int o = 0; o < COUT; ++o) acc[o] = fmaf(w, u[o], acc[o]);
        }
    }

    float* pp = part + ((size_t)wid * BATCH + lane) * PART_STRIDE;
    #pragma unroll
    for (int q = 0; q < 4; ++q)
        reinterpret_cast<float4*>(pp)[q] =
            make_float4(acc[q*4+0], acc[q*4+1], acc[q*4+2], acc[q*4+3]);
    pp[16] = z;
}

// ---------------- merge partials, squash, update vsum / write out ----------------
template<int PASS>
__global__ __launch_bounds__(256) void k_merge(const float* __restrict__ part,
                                               float* __restrict__ vsum,
                                               float* __restrict__ out) {
    __shared__ float R[3][PART_STRIDE];
    int bid = blockIdx.x;                  // 0..639 = c*64 + b
    int c = bid >> 6;
    int b = bid & 63;
    int t = threadIdx.x;

    float a[COUT];
    #pragma unroll
    for (int o = 0; o < COUT; ++o) a[o] = 0.f;
    float z = 0.f;

    for (int ch = t; ch < NSLICES; ch += 256) {
        // record index for (c, slice=ch) is ch*NCAPS + c (k_pass wid ordering)
        const float* pp = part + ((size_t)(ch * NCAPS + c) * BATCH + b) * PART_STRIDE;
        float4 q0 = reinterpret_cast<const float4*>(pp)[0];
        float4 q1 = reinterpret_cast<const float4*>(pp)[1];
        float4 q2 = reinterpret_cast<const float4*>(pp)[2];
        float4 q3 = reinterpret_cast<const float4*>(pp)[3];
        a[0]+=q0.x; a[1]+=q0.y; a[2]+=q0.z; a[3]+=q0.w;
        a[4]+=q1.x; a[5]+=q1.y; a[6]+=q1.z; a[7]+=q1.w;
        a[8]+=q2.x; a[9]+=q2.y; a[10]+=q2.z; a[11]+=q2.w;
        a[12]+=q3.x; a[13]+=q3.y; a[14]+=q3.z; a[15]+=q3.w;
        z += pp[16];
    }

    #pragma unroll
    for (int off = 32; off >= 1; off >>= 1) {
        z += __shfl_xor(z, off);
        #pragma unroll
        for (int o = 0; o < COUT; ++o) a[o] += __shfl_xor(a[o], off);
    }

    int wid = t >> 6, lane = t & 63;
    if (lane == 0 && wid > 0) {
        #pragma unroll
        for (int o = 0; o < COUT; ++o) R[wid - 1][o] = a[o];
        R[wid - 1][16] = z;
    }
    __syncthreads();
    if (t == 0) {
        #pragma unroll
        for (int r = 0; r < 3; ++r) {
            #pragma unroll
            for (int o = 0; o < COUT; ++o) a[o] += R[r][o];
            z += R[r][16];
        }
        float s[COUT];
        float sn = 0.f;
        #pragma unroll
        for (int o = 0; o < COUT; ++o) { s[o] = a[o] / z; sn += s[o] * s[o]; }
        float scale = sn / ((1.f + sn) * sqrtf(sn));   // |s|^2/(1+|s|^2) * 1/|s|
        if (PASS == 0) {
            float* vp = vsum + ((size_t)(c * BATCH) + b) * COUT;
            #pragma unroll
            for (int o = 0; o < COUT; ++o) vp[o] = scale * s[o];
        } else if (PASS == 1) {
            float* vp = vsum + ((size_t)(c * BATCH) + b) * COUT;
            #pragma unroll
            for (int o = 0; o < COUT; ++o) vp[o] += scale * s[o];
        } else {
            float* op = out + ((size_t)(b * NCAPS + c)) * COUT;
            #pragma unroll
            for (int o = 0; o < COUT; ++o) op[o] = scale * s[o];
        }
    }
}

extern "C" void kernel_launch(void* const* d_in, const int* in_sizes, int n_in,
                              void* d_out, int out_size, void* d_ws, size_t ws_size,
                              hipStream_t stream) {
    const float* x = (const float*)d_in[0];   // [64, 6272, 8]
    const float* W = (const float*)d_in[1];   // [10, 6272, 8, 16]
    float* out = (float*)d_out;               // [64, 10, 1, 16]

    // ws layout: Whp [4,014,080 u32] | xTh [1,604,096 u32] | part | vsum
    unsigned* Whp = (unsigned*)d_ws;
    unsigned* xTh = Whp + WUINTS;
    float* part = (float*)d_ws + PREP_TOTAL;
    float* vsum = part + (size_t)NCAPS * NSLICES * BATCH * PART_STRIDE;

    k_prep<<<2048, 256, 0, stream>>>(x, W, Whp, xTh);

    k_pass<0><<<NCAPS * NSLICES / 4, 256, 0, stream>>>(Whp, xTh, vsum, part);
    k_merge<0><<<NCAPS * BATCH, 256, 0, stream>>>(part, vsum, out);

    k_pass<1><<<NCAPS * NSLICES / 4, 256, 0, stream>>>(Whp, xTh, vsum, part);
    k_merge<1><<<NCAPS * BATCH, 256, 0, stream>>>(part, vsum, out);

    k_pass<2><<<NCAPS * NSLICES / 4, 256, 0, stream>>>(Whp, xTh, vsum, part);
    k_merge<2><<<NCAPS * BATCH, 256, 0, stream>>>(part, vsum, out);
}

// Round 7
// 193.808 us; speedup vs baseline: 1.6884x; 1.1652x over previous
//
#include <hip/hip_runtime.h>
#include <math.h>

#define NODES  6272
#define BATCH  64
#define NCAPS  10
#define NPAIRS 3136               // node pairs
#define STRIPS 392                // NPAIRS / PPW
#define PPW    8                  // pairs per wave per pass
#define REC    12                 // partial record: 8 s + z + pad

typedef decltype(__builtin_amdgcn_cvt_pkrtz(0.f, 0.f)) h2t;
typedef _Float16 f16x8 __attribute__((ext_vector_type(8)));
typedef float    f32x16 __attribute__((ext_vector_type(16)));

static __device__ inline unsigned packh2(float a, float b) {
    union { h2t h; unsigned u; } cv;
    cv.h = __builtin_amdgcn_cvt_pkrtz(a, b);
    return cv.u;
}
static __device__ inline f16x8 asf16(uint4 v) {
    union { uint4 u; f16x8 h; } cv; cv.u = v; return cv.h;
}

// ---- prep W: Wd[(c*NODES+n)*16+o] = uint4 of f16 pairs (i0,i1)(i2,i3)(i4,i5)(i6,i7)
__global__ __launch_bounds__(256) void k_prepW(const float* __restrict__ W,
                                               uint4* __restrict__ Wd) {
    int g = blockIdx.x * 256 + threadIdx.x;         // 0 .. 1,003,519
    int o = g & 15;
    size_t cn = (size_t)(g >> 4);                   // c*NODES + n
    const float* wp = W + cn * 128 + o;             // W[c][n][i][o], i stride 16
    Wd[g] = make_uint4(packh2(wp[0],  wp[16]),
                       packh2(wp[32], wp[48]),
                       packh2(wp[64], wp[80]),
                       packh2(wp[96], wp[112]));
}

// ---- prep x: B-fragments. xf[(pair*2+bhalf)*64+lane] = x[b= bhalf*32+(lane&31)][n=2*pair+(lane>>5)][0..7]
__global__ __launch_bounds__(256) void k_prepX(const float* __restrict__ x,
                                               uint4* __restrict__ xf) {
    int g = blockIdx.x * 256 + threadIdx.x;         // 0 .. 401,407
    int lane  = g & 63;
    int pb    = g >> 6;
    int bhalf = pb & 1;
    int pair  = pb >> 1;
    int b = bhalf * 32 + (lane & 31);
    int n = pair * 2 + (lane >> 5);
    const float* xp = x + ((size_t)b * NODES + n) * 8;
    float4 lo = *reinterpret_cast<const float4*>(xp);
    float4 hi = *reinterpret_cast<const float4*>(xp + 4);
    xf[g] = make_uint4(packh2(lo.x, lo.y), packh2(lo.z, lo.w),
                       packh2(hi.x, hi.y), packh2(hi.z, hi.w));
}

// ---- routing pass: wave = (c, bhalf, strip of 8 node-pairs); 1 MFMA per pair.
// A = block-diag(W_n0, W_n1) built by zeroing inactive lanes; B = x frag.
// C: regs 0-7 node0, 8-15 node1; o(q) = (q&3)+8*(q>>2)+4*(lane>>5).
template<int PASS>
__global__ __launch_bounds__(256) void k_pass(const uint4* __restrict__ Wd,
                                              const uint4* __restrict__ xf,
                                              const float* __restrict__ vsum,
                                              float* __restrict__ part) {
    int wid   = blockIdx.x * 4 + (threadIdx.x >> 6);   // 0 .. 7839
    int lane  = threadIdx.x & 63;
    int strip = wid / 20;
    int rem   = wid % 20;
    int c     = rem >> 1;
    int bhalf = rem & 1;
    int h     = lane >> 5;
    int m31   = lane & 31;
    bool active = ((m31 >> 4) == h);                   // lane carries W (else zeros)

    const uint4* wsrc = Wd + ((size_t)c * NODES + (size_t)2 * strip * PPW + h) * 16 + (m31 & 15);
    const uint4* xsrc = xf + ((size_t)(strip * PPW) * 2 + bhalf) * 64 + lane;

    float vsl[8];
    if (PASS > 0) {
        int b = bhalf * 32 + m31;
        const float* vp = vsum + ((size_t)c * BATCH + b) * 16 + 4 * h;
        float4 v0 = *reinterpret_cast<const float4*>(vp);       // o = 4h..4h+3
        float4 v1 = *reinterpret_cast<const float4*>(vp + 8);   // o = 8+4h..
        vsl[0]=v0.x; vsl[1]=v0.y; vsl[2]=v0.z; vsl[3]=v0.w;
        vsl[4]=v1.x; vsl[5]=v1.y; vsl[6]=v1.z; vsl[7]=v1.w;
    }

    uint4 zu = make_uint4(0, 0, 0, 0);
    uint4 aw = wsrc[0];
    uint4 bx = xsrc[0];
    if (!active) aw = zu;

    f32x16 Cacc = {};              // PASS==0: MFMA C-chaining
    float acc[16];
    #pragma unroll
    for (int q = 0; q < 16; ++q) acc[q] = 0.f;
    float z = 0.f;

    #pragma unroll
    for (int s = 0; s < PPW; ++s) {
        uint4 awn = zu, bxn = zu;
        if (s + 1 < PPW) {                               // prefetch next pair
            awn = wsrc[(size_t)(s + 1) * 32];
            bxn = xsrc[(size_t)(s + 1) * 128];
            if (!active) awn = zu;
        }
        if (PASS == 0) {
            Cacc = __builtin_amdgcn_mfma_f32_32x32x16_f16(asf16(aw), asf16(bx), Cacc, 0, 0, 0);
        } else {
            f32x16 Cz = {};
            f32x16 Cr = __builtin_amdgcn_mfma_f32_32x32x16_f16(asf16(aw), asf16(bx), Cz, 0, 0, 0);
            float lg0 = 0.f, lg1 = 0.f;
            #pragma unroll
            for (int q = 0; q < 8; ++q) {
                lg0 = fmaf(Cr[q],     vsl[q], lg0);
                lg1 = fmaf(Cr[q + 8], vsl[q], lg1);
            }
            lg0 += __shfl_xor(lg0, 32);                  // join o-halves
            lg1 += __shfl_xor(lg1, 32);
            float w0 = __expf(lg0), w1 = __expf(lg1);    // |lg| small; fp32-safe
            z += w0 + w1;
            #pragma unroll
            for (int q = 0; q < 8; ++q) {
                acc[q]     = fmaf(w0, Cr[q],     acc[q]);
                acc[q + 8] = fmaf(w1, Cr[q + 8], acc[q + 8]);
            }
        }
        aw = awn; bx = bxn;
    }

    float sv[8];
    if (PASS == 0) {
        #pragma unroll
        for (int q = 0; q < 8; ++q) sv[q] = Cacc[q] + Cacc[q + 8];
        z = 2.f * PPW;                                   // 16 nodes, weight 1
    } else {
        #pragma unroll
        for (int q = 0; q < 8; ++q) sv[q] = acc[q] + acc[q + 8];
    }
    float* pp = part + (((size_t)(c * 2 + bhalf) * STRIPS + strip) * 64 + lane) * REC;
    *reinterpret_cast<float4*>(pp)     = make_float4(sv[0], sv[1], sv[2], sv[3]);
    *reinterpret_cast<float4*>(pp + 4) = make_float4(sv[4], sv[5], sv[6], sv[7]);
    pp[8] = z;
}

// ---- merge: block per (c,b); sum strip records, squash, update vsum / out
template<int PASS>
__global__ __launch_bounds__(256) void k_merge(const float* __restrict__ part,
                                               float* __restrict__ vsum,
                                               float* __restrict__ out) {
    __shared__ float R[3][20];
    int bid = blockIdx.x;                  // 0..639 = c*64 + b
    int c = bid >> 6;
    int b = bid & 63;
    int bhalf = b >> 5;
    int l0 = b & 31;
    int t = threadIdx.x;

    float sv[16];
    #pragma unroll
    for (int o = 0; o < 16; ++o) sv[o] = 0.f;
    float z = 0.f;

    for (int s = t; s < STRIPS; s += 256) {
        const float* pA = part + (((size_t)(c * 2 + bhalf) * STRIPS + s) * 64 + l0) * REC;
        const float* pB = pA + 32 * REC;   // partner lane (+32): o-set +4
        float4 a0 = reinterpret_cast<const float4*>(pA)[0];
        float4 a1 = reinterpret_cast<const float4*>(pA)[1];
        float4 b0 = reinterpret_cast<const float4*>(pB)[0];
        float4 b1 = reinterpret_cast<const float4*>(pB)[1];
        z += pA[8];
        sv[0]+=a0.x;  sv[1]+=a0.y;  sv[2]+=a0.z;  sv[3]+=a0.w;    // o 0..3
        sv[8]+=a1.x;  sv[9]+=a1.y;  sv[10]+=a1.z; sv[11]+=a1.w;   // o 8..11
        sv[4]+=b0.x;  sv[5]+=b0.y;  sv[6]+=b0.z;  sv[7]+=b0.w;    // o 4..7
        sv[12]+=b1.x; sv[13]+=b1.y; sv[14]+=b1.z; sv[15]+=b1.w;   // o 12..15
    }

    #pragma unroll
    for (int off = 32; off >= 1; off >>= 1) {
        z += __shfl_xor(z, off);
        #pragma unroll
        for (int o = 0; o < 16; ++o) sv[o] += __shfl_xor(sv[o], off);
    }

    int wv = t >> 6, lane = t & 63;
    if (lane == 0 && wv > 0) {
        #pragma unroll
        for (int o = 0; o < 16; ++o) R[wv - 1][o] = sv[o];
        R[wv - 1][16] = z;
    }
    __syncthreads();
    if (t == 0) {
        #pragma unroll
        for (int r = 0; r < 3; ++r) {
            #pragma unroll
            for (int o = 0; o < 16; ++o) sv[o] += R[r][o];
            z += R[r][16];
        }
        float s[16];
        float sn = 0.f;
        #pragma unroll
        for (int o = 0; o < 16; ++o) { s[o] = sv[o] / z; sn += s[o] * s[o]; }
        float scale = sn / ((1.f + sn) * sqrtf(sn));   // |s|^2/(1+|s|^2) / |s|
        if (PASS == 0) {
            float* vp = vsum + ((size_t)(c * BATCH) + b) * 16;
            #pragma unroll
            for (int o = 0; o < 16; ++o) vp[o] = scale * s[o];
        } else if (PASS == 1) {
            float* vp = vsum + ((size_t)(c * BATCH) + b) * 16;
            #pragma unroll
            for (int o = 0; o < 16; ++o) vp[o] += scale * s[o];
        } else {
            float* op = out + ((size_t)(b * NCAPS + c)) * 16;
            #pragma unroll
            for (int o = 0; o < 16; ++o) op[o] = scale * s[o];
        }
    }
}

extern "C" void kernel_launch(void* const* d_in, const int* in_sizes, int n_in,
                              void* d_out, int out_size, void* d_ws, size_t ws_size,
                              hipStream_t stream) {
    const float* x = (const float*)d_in[0];   // [64, 6272, 8]
    const float* W = (const float*)d_in[1];   // [10, 6272, 8, 16]
    float* out = (float*)d_out;               // [64, 10, 1, 16]

    // ws: Wd 1,003,520 uint4 | xf 401,408 uint4 | part 10*2*392*64*12 f | vsum 10*64*16 f
    uint4* Wd = (uint4*)d_ws;
    uint4* xf = Wd + (size_t)NCAPS * NODES * 16;                 // +1,003,520
    float* part = (float*)(xf + (size_t)NPAIRS * 2 * 64);        // +401,408
    float* vsum = part + (size_t)NCAPS * 2 * STRIPS * 64 * REC;  // +6,021,120

    k_prepW<<<3920, 256, 0, stream>>>(W, Wd);
    k_prepX<<<1568, 256, 0, stream>>>(x, xf);

    k_pass<0><<<1960, 256, 0, stream>>>(Wd, xf, vsum, part);
    k_merge<0><<<NCAPS * BATCH, 256, 0, stream>>>(part, vsum, out);

    k_pass<1><<<1960, 256, 0, stream>>>(Wd, xf, vsum, part);
    k_merge<1><<<NCAPS * BATCH, 256, 0, stream>>>(part, vsum, out);

    k_pass<2><<<1960, 256, 0, stream>>>(Wd, xf, vsum, part);
    k_merge<2><<<NCAPS * BATCH, 256, 0, stream>>>(part, vsum, out);
}

// Round 8
// 183.340 us; speedup vs baseline: 1.7847x; 1.0571x over previous
//
#include <hip/hip_runtime.h>
#include <math.h>

#define NODES  6272
#define BATCH  64
#define NCAPS  10
#define NPAIRS 3136               // node pairs
#define STRIPS 392                // NPAIRS / PPW
#define PPW    8                  // pairs per wave per pass
#define REC    12                 // partial record: 8 s + z + pad

#define WQUADS (NCAPS * NODES * 16)   // Wd uint4 count = 1,003,520
#define XQUADS (NPAIRS * 2 * 64)      // xf uint4 count =   401,408

typedef decltype(__builtin_amdgcn_cvt_pkrtz(0.f, 0.f)) h2t;
typedef _Float16 f16x8 __attribute__((ext_vector_type(8)));
typedef float    f32x16 __attribute__((ext_vector_type(16)));

static __device__ inline unsigned packh2(float a, float b) {
    union { h2t h; unsigned u; } cv;
    cv.h = __builtin_amdgcn_cvt_pkrtz(a, b);
    return cv.u;
}
static __device__ inline f16x8 asf16(uint4 v) {
    union { uint4 u; f16x8 h; } cv; cv.u = v; return cv.h;
}

// ---- combined prep:
// Wd[(c*NODES+n)*16+o] = uint4 f16-pairs (i0,i1)(i2,i3)(i4,i5)(i6,i7)
// xf[(pair*2+bhalf)*64+lane] = x[b=bhalf*32+(lane&31)][n=2*pair+(lane>>5)][0..7]
__global__ __launch_bounds__(256) void k_prep(const float* __restrict__ x,
                                              const float* __restrict__ W,
                                              uint4* __restrict__ Wd,
                                              uint4* __restrict__ xf) {
    for (int g = blockIdx.x * 256 + threadIdx.x; g < WQUADS + XQUADS;
         g += gridDim.x * 256) {
        if (g < WQUADS) {
            int o = g & 15;
            size_t cn = (size_t)(g >> 4);               // c*NODES + n
            const float* wp = W + cn * 128 + o;         // W[c][n][i][o], i stride 16
            Wd[g] = make_uint4(packh2(wp[0],  wp[16]),
                               packh2(wp[32], wp[48]),
                               packh2(wp[64], wp[80]),
                               packh2(wp[96], wp[112]));
        } else {
            int G = g - WQUADS;
            int lane  = G & 63;
            int pb    = G >> 6;
            int bhalf = pb & 1;
            int pair  = pb >> 1;
            int b = bhalf * 32 + (lane & 31);
            int n = pair * 2 + (lane >> 5);
            const float* xp = x + ((size_t)b * NODES + n) * 8;
            float4 lo = *reinterpret_cast<const float4*>(xp);
            float4 hi = *reinterpret_cast<const float4*>(xp + 4);
            xf[G] = make_uint4(packh2(lo.x, lo.y), packh2(lo.z, lo.w),
                               packh2(hi.x, hi.y), packh2(hi.z, hi.w));
        }
    }
}

// ---- routing pass: block = 640 thr = 10 waves (wave id = c), shared (bhalf,strip).
// All 10 waves read the SAME xf strip (L1 reuse); each wave its own c's Wd.
// A = block-diag(W_n0, W_n1) via lane-zeroing; B = x frag; 1 MFMA per node-pair.
// C: regs 0-7 node0, 8-15 node1; o(q) = (q&3)+8*(q>>2)+4*(lane>>5).
template<int PASS>
__global__ __launch_bounds__(640) void k_pass(const uint4* __restrict__ Wd,
                                              const uint4* __restrict__ xf,
                                              const float* __restrict__ vsum,
                                              float* __restrict__ part) {
    int bid   = blockIdx.x;                 // 0 .. 783
    int bhalf = bid & 1;
    int strip = bid >> 1;
    int c     = threadIdx.x >> 6;           // wave id = capsule
    int lane  = threadIdx.x & 63;
    int h     = lane >> 5;
    int m31   = lane & 31;
    bool active = ((m31 >> 4) == h);        // lane carries W (else zeros)

    const uint4* wsrc = Wd + ((size_t)c * NODES + (size_t)2 * strip * PPW + h) * 16 + (m31 & 15);
    const uint4* xsrc = xf + ((size_t)(strip * PPW) * 2 + bhalf) * 64 + lane;

    float vsl[8];
    if (PASS > 0) {
        int b = bhalf * 32 + m31;
        const float* vp = vsum + ((size_t)c * BATCH + b) * 16 + 4 * h;
        float4 v0 = *reinterpret_cast<const float4*>(vp);       // o = 4h..4h+3
        float4 v1 = *reinterpret_cast<const float4*>(vp + 8);   // o = 8+4h..
        vsl[0]=v0.x; vsl[1]=v0.y; vsl[2]=v0.z; vsl[3]=v0.w;
        vsl[4]=v1.x; vsl[5]=v1.y; vsl[6]=v1.z; vsl[7]=v1.w;
    }

    uint4 zu = make_uint4(0, 0, 0, 0);
    uint4 aw = wsrc[0];
    uint4 bx = xsrc[0];
    if (!active) aw = zu;

    f32x16 Cacc = {};              // PASS==0: MFMA C-chaining
    float acc[16];
    #pragma unroll
    for (int q = 0; q < 16; ++q) acc[q] = 0.f;
    float z = 0.f;

    #pragma unroll
    for (int s = 0; s < PPW; ++s) {
        uint4 awn = zu, bxn = zu;
        if (s + 1 < PPW) {                               // prefetch next pair
            awn = wsrc[(size_t)(s + 1) * 32];
            bxn = xsrc[(size_t)(s + 1) * 128];
            if (!active) awn = zu;
        }
        if (PASS == 0) {
            Cacc = __builtin_amdgcn_mfma_f32_32x32x16_f16(asf16(aw), asf16(bx), Cacc, 0, 0, 0);
        } else {
            f32x16 Cz = {};
            f32x16 Cr = __builtin_amdgcn_mfma_f32_32x32x16_f16(asf16(aw), asf16(bx), Cz, 0, 0, 0);
            float lg0 = 0.f, lg1 = 0.f;
            #pragma unroll
            for (int q = 0; q < 8; ++q) {
                lg0 = fmaf(Cr[q],     vsl[q], lg0);
                lg1 = fmaf(Cr[q + 8], vsl[q], lg1);
            }
            lg0 += __shfl_xor(lg0, 32);                  // join o-halves
            lg1 += __shfl_xor(lg1, 32);
            float w0 = __expf(lg0), w1 = __expf(lg1);    // |lg| small; fp32-safe
            z += w0 + w1;
            #pragma unroll
            for (int q = 0; q < 8; ++q) {
                acc[q]     = fmaf(w0, Cr[q],     acc[q]);
                acc[q + 8] = fmaf(w1, Cr[q + 8], acc[q + 8]);
            }
        }
        aw = awn; bx = bxn;
    }

    float sv[8];
    if (PASS == 0) {
        #pragma unroll
        for (int q = 0; q < 8; ++q) sv[q] = Cacc[q] + Cacc[q + 8];
        z = 2.f * PPW;                                   // 16 nodes, weight 1
    } else {
        #pragma unroll
        for (int q = 0; q < 8; ++q) sv[q] = acc[q] + acc[q + 8];
    }
    float* pp = part + (((size_t)(c * 2 + bhalf) * STRIPS + strip) * 64 + lane) * REC;
    *reinterpret_cast<float4*>(pp)     = make_float4(sv[0], sv[1], sv[2], sv[3]);
    *reinterpret_cast<float4*>(pp + 4) = make_float4(sv[4], sv[5], sv[6], sv[7]);
    pp[8] = z;
}

// ---- merge: block per (c,b); sum strip records, squash, update vsum / out
template<int PASS>
__global__ __launch_bounds__(256) void k_merge(const float* __restrict__ part,
                                               float* __restrict__ vsum,
                                               float* __restrict__ out) {
    __shared__ float R[3][20];
    int bid = blockIdx.x;                  // 0..639 = c*64 + b
    int c = bid >> 6;
    int b = bid & 63;
    int bhalf = b >> 5;
    int l0 = b & 31;
    int t = threadIdx.x;

    float sv[16];
    #pragma unroll
    for (int o = 0; o < 16; ++o) sv[o] = 0.f;
    float z = 0.f;

    for (int s = t; s < STRIPS; s += 256) {
        const float* pA = part + (((size_t)(c * 2 + bhalf) * STRIPS + s) * 64 + l0) * REC;
        const float* pB = pA + 32 * REC;   // partner lane (+32): o-set +4
        float4 a0 = reinterpret_cast<const float4*>(pA)[0];
        float4 a1 = reinterpret_cast<const float4*>(pA)[1];
        float4 b0 = reinterpret_cast<const float4*>(pB)[0];
        float4 b1 = reinterpret_cast<const float4*>(pB)[1];
        z += pA[8];
        sv[0]+=a0.x;  sv[1]+=a0.y;  sv[2]+=a0.z;  sv[3]+=a0.w;    // o 0..3
        sv[8]+=a1.x;  sv[9]+=a1.y;  sv[10]+=a1.z; sv[11]+=a1.w;   // o 8..11
        sv[4]+=b0.x;  sv[5]+=b0.y;  sv[6]+=b0.z;  sv[7]+=b0.w;    // o 4..7
        sv[12]+=b1.x; sv[13]+=b1.y; sv[14]+=b1.z; sv[15]+=b1.w;   // o 12..15
    }

    #pragma unroll
    for (int off = 32; off >= 1; off >>= 1) {
        z += __shfl_xor(z, off);
        #pragma unroll
        for (int o = 0; o < 16; ++o) sv[o] += __shfl_xor(sv[o], off);
    }

    int wv = t >> 6, lane = t & 63;
    if (lane == 0 && wv > 0) {
        #pragma unroll
        for (int o = 0; o < 16; ++o) R[wv - 1][o] = sv[o];
        R[wv - 1][16] = z;
    }
    __syncthreads();
    if (t == 0) {
        #pragma unroll
        for (int r = 0; r < 3; ++r) {
            #pragma unroll
            for (int o = 0; o < 16; ++o) sv[o] += R[r][o];
            z += R[r][16];
        }
        float s[16];
        float sn = 0.f;
        #pragma unroll
        for (int o = 0; o < 16; ++o) { s[o] = sv[o] / z; sn += s[o] * s[o]; }
        float scale = sn / ((1.f + sn) * sqrtf(sn));   // |s|^2/(1+|s|^2) / |s|
        if (PASS == 0) {
            float* vp = vsum + ((size_t)(c * BATCH) + b) * 16;
            #pragma unroll
            for (int o = 0; o < 16; ++o) vp[o] = scale * s[o];
        } else if (PASS == 1) {
            float* vp = vsum + ((size_t)(c * BATCH) + b) * 16;
            #pragma unroll
            for (int o = 0; o < 16; ++o) vp[o] += scale * s[o];
        } else {
            float* op = out + ((size_t)(b * NCAPS + c)) * 16;
            #pragma unroll
            for (int o = 0; o < 16; ++o) op[o] = scale * s[o];
        }
    }
}

extern "C" void kernel_launch(void* const* d_in, const int* in_sizes, int n_in,
                              void* d_out, int out_size, void* d_ws, size_t ws_size,
                              hipStream_t stream) {
    const float* x = (const float*)d_in[0];   // [64, 6272, 8]
    const float* W = (const float*)d_in[1];   // [10, 6272, 8, 16]
    float* out = (float*)d_out;               // [64, 10, 1, 16]

    // ws: Wd 1,003,520 uint4 | xf 401,408 uint4 | part 10*2*392*64*12 f | vsum 10*64*16 f
    uint4* Wd = (uint4*)d_ws;
    uint4* xf = Wd + (size_t)WQUADS;
    float* part = (float*)(xf + (size_t)XQUADS);
    float* vsum = part + (size_t)NCAPS * 2 * STRIPS * 64 * REC;

    k_prep<<<2048, 256, 0, stream>>>(x, W, Wd, xf);

    k_pass<0><<<2 * STRIPS, 640, 0, stream>>>(Wd, xf, vsum, part);
    k_merge<0><<<NCAPS * BATCH, 256, 0, stream>>>(part, vsum, out);

    k_pass<1><<<2 * STRIPS, 640, 0, stream>>>(Wd, xf, vsum, part);
    k_merge<1><<<NCAPS * BATCH, 256, 0, stream>>>(part, vsum, out);

    k_pass<2><<<2 * STRIPS, 640, 0, stream>>>(Wd, xf, vsum, part);
    k_merge<2><<<NCAPS * BATCH, 256, 0, stream>>>(part, vsum, out);
}